// Round 9
// baseline (91.423 us; speedup 1.0000x reference)
//
#include <hip/hip_runtime.h>

#define N_NODES 40000
#define N_EDGES 160000
#define N_FEATS 74
#define DD 1024
#define HD 3072
#define N_GRAPHS 800

// kPre geometry: 192 v-slices of 16, then 57 blocks of L/R wave-tasks
#define NSLICE 192
#define SLICE_D 16
#define NBLK_LR 57          // ceil((222+1)/4)
// kScan geometry: owner-computes binning
#define NC 4                // edge chunks
#define NR 250              // dst ranges (one owner WG per (c,r))
#define RNG 160             // dsts per range  (RNG*NR == N_NODES)
#define ECH 40000           // edges per chunk (ECH*NC == N_EDGES)

__device__ __forceinline__ float waveReduceSum(float v) {
    #pragma unroll
    for (int off = 32; off > 0; off >>= 1)
        v += __shfl_down(v, off, 64);
    return v;
}
// sums lanes 0..15 into lane 0 (lanes >=16 must hold 0)
__device__ __forceinline__ float reduce16(float v) {
    #pragma unroll
    for (int off = 8; off > 0; off >>= 1)
        v += __shfl_down(v, off, 64);
    return v;
}
__device__ __forceinline__ float lrelu02(float x) { return x > 0.f ? x : 0.2f * x; }

// ---- K1 kPre: fused weight precompute, no inter-kernel dependency ----
// blocks [0,192): slice s -> vs[16] = W1-rows@W2; wvpar[(h*74+f)*64 + s%64];
//                 bgvpar[s] = bias[slice].vs
// blocks [192,249): wave-tasks t<222 -> wlr[f*6+{h,3+h}] = L/R dots; t==222 -> c0
__global__ __launch_bounds__(256) void kPre(
    const float* __restrict__ W1, const float* __restrict__ W2,
    const float* __restrict__ b1, const float* __restrict__ b2,
    const float* __restrict__ W, const float* __restrict__ al,
    const float* __restrict__ ar, const float* __restrict__ bias,
    float* __restrict__ wlr, float* __restrict__ c0,
    float* __restrict__ bgvpar, float* __restrict__ wvpar) {
    int wave = threadIdx.x >> 6, lane = threadIdx.x & 63;
    if (blockIdx.x < NSLICE) {
        __shared__ float vs[SLICE_D];
        int s = blockIdx.x;
        int h = s >> 6;                 // 64 slices per head
        int dbase = s * SLICE_D;        // flat index into [0,3072)
        #pragma unroll
        for (int q = 0; q < 4; ++q) {
            int dg = dbase + wave * 4 + q;
            const float* row = W1 + (size_t)dg * DD;
            float acc = 0.f;
            for (int t = lane; t < DD; t += 64) acc += row[t] * W2[t];
            acc = waveReduceSum(acc);
            if (!lane) vs[wave * 4 + q] = acc;
        }
        __syncthreads();
        float vsl = (lane < SLICE_D) ? vs[lane] : 0.f;
        for (int f = wave; f < N_FEATS; f += 4) {
            float p = (lane < SLICE_D) ? W[(size_t)f * HD + dbase + lane] * vsl : 0.f;
            p = reduce16(p);
            if (!lane) wvpar[((size_t)h * N_FEATS + f) * 64 + (s & 63)] = p;
        }
        if (wave == 0) {
            float p = (lane < SLICE_D) ? bias[dbase + lane] * vsl : 0.f;
            p = reduce16(p);
            if (!lane) bgvpar[s] = p;
        }
    } else {
        int t = (blockIdx.x - NSLICE) * 4 + wave;
        if (t < N_FEATS * 3) {
            int f = t / 3, h = t - f * 3;
            const float* rw = W + (size_t)f * HD + h * DD;
            const float* pl = al + h * DD;
            const float* pr = ar + h * DD;
            float aL = 0.f, aR = 0.f;
            for (int tt = lane; tt < DD; tt += 64) {
                float x = rw[tt];
                aL += x * pl[tt]; aR += x * pr[tt];
            }
            aL = waveReduceSum(aL); aR = waveReduceSum(aR);
            if (!lane) { wlr[f * 6 + h] = aL; wlr[f * 6 + 3 + h] = aR; }
        } else if (t == N_FEATS * 3) {
            float acc = 0.f;
            for (int tt = lane; tt < DD; tt += 64) acc += b1[tt] * W2[tt];
            acc = waveReduceSum(acc);
            if (!lane) *c0 = acc + b2[0];
        }
    }
}

// ---- K2 kNode: node projections; builds lw from wlr + summed wvpar ----
__global__ __launch_bounds__(256) void kNode(const float* __restrict__ feats,
                      const float* __restrict__ wlr, const float* __restrict__ wvpar,
                      float4* __restrict__ sn4,   // [N][2]: {el0..2,_},{hv0..2,_}
                      float4* __restrict__ er4) { // [N]
    __shared__ float tile[256 * 75];
    __shared__ float lw[N_FEATS * 9];
    int t = threadIdx.x;
    int base = blockIdx.x * 256;
    int nvalid = min(256, N_NODES - base);
    for (int i = t; i < N_FEATS * 6; i += 256)
        lw[(i / 6) * 9 + (i % 6)] = wlr[i];
    for (int j = t; j < N_FEATS * 3; j += 256) {       // j = h*74+f
        int h = j / N_FEATS, f = j - h * N_FEATS;
        const float4* q = (const float4*)(wvpar + (size_t)j * 64);
        float s = 0.f;
        #pragma unroll
        for (int k = 0; k < 16; ++k) {
            float4 p = q[k];
            s += p.x + p.y + p.z + p.w;
        }
        lw[f * 9 + 6 + h] = s;
    }
    int total = nvalid * N_FEATS;
    const float* srcp = feats + (size_t)base * N_FEATS;
    for (int i = t; i < total; i += 256) {
        int node = i / N_FEATS;
        int f = i - node * N_FEATS;
        tile[node * 75 + f] = srcp[i];
    }
    __syncthreads();
    if (t < nvalid) {
        float a0=0,a1=0,a2=0,a3=0,a4=0,a5=0,a6=0,a7=0,a8=0;
        const float* row = tile + t * 75;
        #pragma unroll 2
        for (int f = 0; f < N_FEATS; ++f) {
            float x = row[f];
            const float* wp = lw + f * 9;
            a0 += x * wp[0]; a1 += x * wp[1]; a2 += x * wp[2];
            a3 += x * wp[3]; a4 += x * wp[4]; a5 += x * wp[5];
            a6 += x * wp[6]; a7 += x * wp[7]; a8 += x * wp[8];
        }
        int i = base + t;
        sn4[i * 2]     = make_float4(a0, a1, a2, 0.f);  // el
        sn4[i * 2 + 1] = make_float4(a6, a7, a8, 0.f);  // hv
        er4[i]         = make_float4(a3, a4, a5, 0.f);
    }
}

// ---- K3 kScan: owner-computes binned scan. WG (c,r) owns range r's slab in
//      chunk c; int4 dst scan, src gathered on match, plain-store flush. ----
__global__ __launch_bounds__(256) void kScan(const int* __restrict__ src,
                      const int* __restrict__ dst,
                      const float4* __restrict__ sn4, const float4* __restrict__ er4,
                      float* __restrict__ par) {
    __shared__ float acc[RNG * 6];   // 3.84 KB
    int c = blockIdx.x & (NC - 1);
    int r = blockIdx.x >> 2;
    for (int i = threadIdx.x; i < RNG * 6; i += 256) acc[i] = 0.f;
    __syncthreads();
    const int rbase = r * RNG;
    const int ebase = c * ECH;
    const int4* dst4 = (const int4*)(dst + ebase);
    for (int i = threadIdx.x; i < ECH / 4; i += 256) {
        int4 d4 = dst4[i];
        int e = ebase + i * 4;
        #pragma unroll
        for (int k = 0; k < 4; ++k) {
            int d = (k == 0) ? d4.x : (k == 1) ? d4.y : (k == 2) ? d4.z : d4.w;
            unsigned rr = (unsigned)(d - rbase);
            if (rr < RNG) {
                int s = src[e + k];
                float4 L = sn4[s * 2];
                float4 V = sn4[s * 2 + 1];
                float4 R = er4[d];
                float e0 = expf(lrelu02(L.x + R.x));
                float e1 = expf(lrelu02(L.y + R.y));
                float e2 = expf(lrelu02(L.z + R.z));
                float* p = acc + rr * 6;
                atomicAdd(p + 0, e0 * V.x);
                atomicAdd(p + 1, e1 * V.y);
                atomicAdd(p + 2, e2 * V.z);
                atomicAdd(p + 3, e0);
                atomicAdd(p + 4, e1);
                atomicAdd(p + 5, e2);
            }
        }
    }
    __syncthreads();
    float2* out2 = (float2*)(par + (size_t)c * (N_NODES * 6) + (size_t)rbase * 6);
    const float2* acc2 = (const float2*)acc;
    for (int i = threadIdx.x; i < RNG * 3; i += 256) out2[i] = acc2[i];
}

// ---- K4 kFinal: wave per graph; sum 4 chunk-partials, softmax-combine,
//      mean-pool, + (sum bgvpar) + c0 ----
__global__ void kFinal(const float* __restrict__ par,
                       const float* __restrict__ bgvpar, const float* __restrict__ c0,
                       float* __restrict__ y) {
    int g = blockIdx.x * 4 + (threadIdx.x >> 6);
    int lane = threadIdx.x & 63;
    float b = bgvpar[lane] + bgvpar[lane + 64] + bgvpar[lane + 128];
    b = waveReduceSum(b);                      // valid at lane 0
    if (g >= N_GRAPHS) return;
    float cacc = 0.f;
    if (lane < 50) {
        size_t node = (size_t)g * 50 + lane;
        float n0=0,n1=0,n2=0,d0=0,d1=0,d2=0;
        #pragma unroll
        for (int cc = 0; cc < NC; ++cc) {
            const float* p = par + (size_t)cc * (N_NODES * 6) + node * 6;
            n0 += p[0]; n1 += p[1]; n2 += p[2];
            d0 += p[3]; d1 += p[4]; d2 += p[5];
        }
        if (d0 > 0.f) cacc = n0 / d0 + n1 / d1 + n2 / d2;
    }
    cacc = waveReduceSum(cacc);
    if (!lane) y[g] = cacc * (1.f / 50.f) + b + c0[0];
}

extern "C" void kernel_launch(void* const* d_in, const int* in_sizes, int n_in,
                              void* d_out, int out_size, void* d_ws, size_t ws_size,
                              hipStream_t stream) {
    const float* feats = (const float*)d_in[0];
    const float* W     = (const float*)d_in[1];
    const float* al    = (const float*)d_in[2];
    const float* ar    = (const float*)d_in[3];
    const float* bias  = (const float*)d_in[4];
    const float* W1    = (const float*)d_in[5];
    const float* b1    = (const float*)d_in[6];
    const float* W2    = (const float*)d_in[7];
    const float* b2    = (const float*)d_in[8];
    const int*   src   = (const int*)d_in[9];
    const int*   dst   = (const int*)d_in[10];

    float* ws     = (float*)d_ws;
    float* wlr    = ws;                    // 444
    float* c0     = ws + 448;              // 1
    float* bgvpar = ws + 512;              // 192
    float* wvpar  = ws + 768;              // 222*64 = 14208
    float* sn     = ws + 16384;            // N*8  (16B aligned)
    float* er     = sn + N_NODES * 8;      // N*4
    float* par    = er + N_NODES * 4;      // NC*N*6 = 960000
    float* y      = (float*)d_out;

    hipLaunchKernelGGL(kPre, dim3(NSLICE + NBLK_LR), dim3(256), 0, stream,
                       W1, W2, b1, b2, W, al, ar, bias, wlr, c0, bgvpar, wvpar);
    hipLaunchKernelGGL(kNode, dim3((N_NODES + 255) / 256), dim3(256), 0, stream,
                       feats, wlr, wvpar, (float4*)sn, (float4*)er);
    hipLaunchKernelGGL(kScan, dim3(NC * NR), dim3(256), 0, stream,
                       src, dst, (const float4*)sn, (const float4*)er, par);
    hipLaunchKernelGGL(kFinal, dim3((N_GRAPHS + 3) / 4), dim3(256), 0, stream,
                       par, bgvpar, c0, y);
}

// Round 10
// 73.626 us; speedup vs baseline: 1.2417x; 1.2417x over previous
//
#include <hip/hip_runtime.h>

#define N_NODES 40000
#define N_EDGES 160000
#define N_FEATS 74
#define DD 1024
#define HD 3072
#define N_GRAPHS 800

// kPre geometry
#define NSLICE 384
#define SLICE_D 8
#define NBLK_LR 57            // ceil((222+1)/4)
// kScan geometry: compact-then-process binning
#define NC 16                 // edge chunks
#define NR 32                 // dst ranges
#define RNG 1250              // dsts per range  (RNG*NR == N_NODES)
#define ECH 10000             // edges per chunk (ECH*NC == N_EDGES)
#define TILE 2048             // edges scanned per compact/process round
#define QCAP TILE

__device__ __forceinline__ float waveReduceSum(float v) {
    #pragma unroll
    for (int off = 32; off > 0; off >>= 1)
        v += __shfl_down(v, off, 64);
    return v;
}
// sums lanes 0..7 into lane 0 (lanes >=8 must hold 0)
__device__ __forceinline__ float reduce8(float v) {
    #pragma unroll
    for (int off = 4; off > 0; off >>= 1)
        v += __shfl_down(v, off, 64);
    return v;
}
__device__ __forceinline__ float lrelu02(float x) { return x > 0.f ? x : 0.2f * x; }

// ---- K1 kPre ----
// blocks [0,384): slice s (8 dims of flat HD) -> vs = W1@W2 slice;
//   wvpar[(h*74+f)*128 + s%128] = W-slice . vs ; bgvpar[s] = bias-slice . vs
// blocks [384,441): wave-tasks t<222 -> wlr[f*6+{h,3+h}]; t==222 -> c0
__global__ __launch_bounds__(256) void kPre(
    const float* __restrict__ W1, const float* __restrict__ W2,
    const float* __restrict__ b1, const float* __restrict__ b2,
    const float* __restrict__ W, const float* __restrict__ al,
    const float* __restrict__ ar, const float* __restrict__ bias,
    float* __restrict__ wlr, float* __restrict__ c0,
    float* __restrict__ bgvpar, float* __restrict__ wvpar) {
    int wave = threadIdx.x >> 6, lane = threadIdx.x & 63;
    if (blockIdx.x < NSLICE) {
        __shared__ float vs[SLICE_D];
        int s = blockIdx.x;
        int h = s >> 7;                  // 128 slices per head
        int dbase = s * SLICE_D;
        #pragma unroll
        for (int q = 0; q < 2; ++q) {
            int dg = dbase + wave * 2 + q;
            const float* row = W1 + (size_t)dg * DD;
            float acc = 0.f;
            for (int t = lane; t < DD; t += 64) acc += row[t] * W2[t];
            acc = waveReduceSum(acc);
            if (!lane) vs[wave * 2 + q] = acc;
        }
        __syncthreads();
        float vsl = (lane < SLICE_D) ? vs[lane] : 0.f;
        for (int f = wave; f < N_FEATS; f += 4) {
            float p = (lane < SLICE_D) ? W[(size_t)f * HD + dbase + lane] * vsl : 0.f;
            p = reduce8(p);
            if (!lane) wvpar[((size_t)h * N_FEATS + f) * 128 + (s & 127)] = p;
        }
        if (wave == 0) {
            float p = (lane < SLICE_D) ? bias[dbase + lane] * vsl : 0.f;
            p = reduce8(p);
            if (!lane) bgvpar[s] = p;
        }
    } else {
        int t = (blockIdx.x - NSLICE) * 4 + wave;
        if (t < N_FEATS * 3) {
            int f = t / 3, h = t - f * 3;
            const float* rw = W + (size_t)f * HD + h * DD;
            const float* pl = al + h * DD;
            const float* pr = ar + h * DD;
            float aL = 0.f, aR = 0.f;
            for (int tt = lane; tt < DD; tt += 64) {
                float x = rw[tt];
                aL += x * pl[tt]; aR += x * pr[tt];
            }
            aL = waveReduceSum(aL); aR = waveReduceSum(aR);
            if (!lane) { wlr[f * 6 + h] = aL; wlr[f * 6 + 3 + h] = aR; }
        } else if (t == N_FEATS * 3) {
            float acc = 0.f;
            for (int tt = lane; tt < DD; tt += 64) acc += b1[tt] * W2[tt];
            acc = waveReduceSum(acc);
            if (!lane) *c0 = acc + b2[0];
        }
    }
}

// ---- K2 kNode: 2 threads per node (f-range split), no feats LDS tile ----
__global__ __launch_bounds__(256) void kNode(const float* __restrict__ feats,
                      const float* __restrict__ wlr, const float* __restrict__ wvpar,
                      float4* __restrict__ sn4, float4* __restrict__ er4) {
    __shared__ float lw[N_FEATS * 9];
    int t = threadIdx.x;
    for (int i = t; i < N_FEATS * 6; i += 256)
        lw[(i / 6) * 9 + (i % 6)] = wlr[i];
    for (int j = t; j < N_FEATS * 3; j += 256) {       // j = h*74+f
        int h = j / N_FEATS, f = j - h * N_FEATS;
        const float4* q = (const float4*)(wvpar + (size_t)j * 128);
        float s = 0.f;
        #pragma unroll
        for (int k = 0; k < 32; ++k) {
            float4 p = q[k];
            s += p.x + p.y + p.z + p.w;
        }
        lw[f * 9 + 6 + h] = s;
    }
    __syncthreads();
    int node = blockIdx.x * 128 + (t >> 1);
    if (node >= N_NODES) return;
    int half = t & 1;
    const float* row = feats + (size_t)node * N_FEATS;
    float a0=0,a1=0,a2=0,a3=0,a4=0,a5=0,a6=0,a7=0,a8=0;
    if (half == 0) {
        // f in [0,36) as float2, then f=36 scalar... cover [0,37)
        #pragma unroll
        for (int k = 0; k < 18; ++k) {
            float2 x2 = *(const float2*)(row + k * 2);
            const float* w0 = lw + (k * 2) * 9;
            a0 += x2.x*w0[0]; a1 += x2.x*w0[1]; a2 += x2.x*w0[2];
            a3 += x2.x*w0[3]; a4 += x2.x*w0[4]; a5 += x2.x*w0[5];
            a6 += x2.x*w0[6]; a7 += x2.x*w0[7]; a8 += x2.x*w0[8];
            const float* w1 = w0 + 9;
            a0 += x2.y*w1[0]; a1 += x2.y*w1[1]; a2 += x2.y*w1[2];
            a3 += x2.y*w1[3]; a4 += x2.y*w1[4]; a5 += x2.y*w1[5];
            a6 += x2.y*w1[6]; a7 += x2.y*w1[7]; a8 += x2.y*w1[8];
        }
        float x = row[36];
        const float* wp = lw + 36 * 9;
        a0 += x*wp[0]; a1 += x*wp[1]; a2 += x*wp[2];
        a3 += x*wp[3]; a4 += x*wp[4]; a5 += x*wp[5];
        a6 += x*wp[6]; a7 += x*wp[7]; a8 += x*wp[8];
    } else {
        float x = row[37];
        const float* wp = lw + 37 * 9;
        a0 += x*wp[0]; a1 += x*wp[1]; a2 += x*wp[2];
        a3 += x*wp[3]; a4 += x*wp[4]; a5 += x*wp[5];
        a6 += x*wp[6]; a7 += x*wp[7]; a8 += x*wp[8];
        #pragma unroll
        for (int k = 0; k < 18; ++k) {
            float2 x2 = *(const float2*)(row + 38 + k * 2);
            const float* w0 = lw + (38 + k * 2) * 9;
            a0 += x2.x*w0[0]; a1 += x2.x*w0[1]; a2 += x2.x*w0[2];
            a3 += x2.x*w0[3]; a4 += x2.x*w0[4]; a5 += x2.x*w0[5];
            a6 += x2.x*w0[6]; a7 += x2.x*w0[7]; a8 += x2.x*w0[8];
            const float* w1 = w0 + 9;
            a0 += x2.y*w1[0]; a1 += x2.y*w1[1]; a2 += x2.y*w1[2];
            a3 += x2.y*w1[3]; a4 += x2.y*w1[4]; a5 += x2.y*w1[5];
            a6 += x2.y*w1[6]; a7 += x2.y*w1[7]; a8 += x2.y*w1[8];
        }
    }
    a0 += __shfl_xor(a0, 1, 64); a1 += __shfl_xor(a1, 1, 64);
    a2 += __shfl_xor(a2, 1, 64); a3 += __shfl_xor(a3, 1, 64);
    a4 += __shfl_xor(a4, 1, 64); a5 += __shfl_xor(a5, 1, 64);
    a6 += __shfl_xor(a6, 1, 64); a7 += __shfl_xor(a7, 1, 64);
    a8 += __shfl_xor(a8, 1, 64);
    if (!half) {
        sn4[node * 2]     = make_float4(a0, a1, a2, 0.f);  // el
        sn4[node * 2 + 1] = make_float4(a6, a7, a8, 0.f);  // hv
        er4[node]         = make_float4(a3, a4, a5, 0.f);
    }
}

// ---- K3 kScan: compact-then-process binned scan ----
__global__ __launch_bounds__(256) void kScan(const int* __restrict__ src,
                      const int* __restrict__ dst,
                      const float4* __restrict__ sn4, const float4* __restrict__ er4,
                      float* __restrict__ par) {
    __shared__ float acc[RNG * 6];   // 30 KB
    __shared__ int queue[QCAP];      // 8 KB
    __shared__ int qcnt;
    int c = blockIdx.x >> 5;
    int r = blockIdx.x & (NR - 1);
    for (int i = threadIdx.x; i < RNG * 6; i += 256) acc[i] = 0.f;
    if (!threadIdx.x) qcnt = 0;
    __syncthreads();
    const int rbase = r * RNG;
    const int ebase = c * ECH;
    const int eend  = ebase + ECH;
    for (int t0 = ebase; t0 < eend; t0 += TILE) {
        // scan + compact (8 strided passes of 256 threads)
        #pragma unroll
        for (int j = 0; j < TILE / 256; ++j) {
            int e = t0 + j * 256 + threadIdx.x;
            if (e < eend) {
                unsigned rr = (unsigned)(dst[e] - rbase);
                if (rr < RNG) {
                    int q = atomicAdd(&qcnt, 1);
                    queue[q] = (e << 11) | (int)rr;
                }
            }
        }
        __syncthreads();
        int n = qcnt;
        // process queue with full waves
        for (int i = threadIdx.x; i < n; i += 256) {
            int pk = queue[i];
            int rr = pk & 2047;
            int e  = pk >> 11;
            int s  = src[e];
            int d  = rbase + rr;
            float4 L = sn4[s * 2];
            float4 V = sn4[s * 2 + 1];
            float4 R = er4[d];
            float e0 = expf(lrelu02(L.x + R.x));
            float e1 = expf(lrelu02(L.y + R.y));
            float e2 = expf(lrelu02(L.z + R.z));
            float* p = acc + rr * 6;
            atomicAdd(p + 0, e0 * V.x);
            atomicAdd(p + 1, e1 * V.y);
            atomicAdd(p + 2, e2 * V.z);
            atomicAdd(p + 3, e0);
            atomicAdd(p + 4, e1);
            atomicAdd(p + 5, e2);
        }
        __syncthreads();
        if (!threadIdx.x) qcnt = 0;
        __syncthreads();
    }
    float2* out2 = (float2*)(par + (size_t)c * (N_NODES * 6) + (size_t)rbase * 6);
    const float2* acc2 = (const float2*)acc;
    for (int i = threadIdx.x; i < RNG * 3; i += 256) out2[i] = acc2[i];
}

// ---- K4 kFinal: wave per graph; sum NC chunk-partials, combine, pool ----
__global__ void kFinal(const float* __restrict__ par,
                       const float* __restrict__ bgvpar, const float* __restrict__ c0,
                       float* __restrict__ y) {
    int g = blockIdx.x * 4 + (threadIdx.x >> 6);
    int lane = threadIdx.x & 63;
    float b = 0.f;
    for (int i = lane; i < NSLICE; i += 64) b += bgvpar[i];
    b = waveReduceSum(b);                      // valid at lane 0
    if (g >= N_GRAPHS) return;
    float cacc = 0.f;
    if (lane < 50) {
        size_t node = (size_t)g * 50 + lane;
        float n0=0,n1=0,n2=0,d0=0,d1=0,d2=0;
        #pragma unroll
        for (int cc = 0; cc < NC; ++cc) {
            const float* p = par + (size_t)cc * (N_NODES * 6) + node * 6;
            n0 += p[0]; n1 += p[1]; n2 += p[2];
            d0 += p[3]; d1 += p[4]; d2 += p[5];
        }
        if (d0 > 0.f) cacc = n0 / d0 + n1 / d1 + n2 / d2;
    }
    cacc = waveReduceSum(cacc);
    if (!lane) y[g] = cacc * (1.f / 50.f) + b + c0[0];
}

extern "C" void kernel_launch(void* const* d_in, const int* in_sizes, int n_in,
                              void* d_out, int out_size, void* d_ws, size_t ws_size,
                              hipStream_t stream) {
    const float* feats = (const float*)d_in[0];
    const float* W     = (const float*)d_in[1];
    const float* al    = (const float*)d_in[2];
    const float* ar    = (const float*)d_in[3];
    const float* bias  = (const float*)d_in[4];
    const float* W1    = (const float*)d_in[5];
    const float* b1    = (const float*)d_in[6];
    const float* W2    = (const float*)d_in[7];
    const float* b2    = (const float*)d_in[8];
    const int*   src   = (const int*)d_in[9];
    const int*   dst   = (const int*)d_in[10];

    float* ws     = (float*)d_ws;
    float* wlr    = ws;                    // 444
    float* c0     = ws + 448;              // 1
    float* bgvpar = ws + 512;              // 384
    float* wvpar  = ws + 1024;             // 222*128 = 28416
    float* sn     = ws + 32768;            // N*8  (16B aligned)
    float* er     = sn + N_NODES * 8;      // N*4
    float* par    = er + N_NODES * 4;      // NC*N*6
    float* y      = (float*)d_out;

    hipLaunchKernelGGL(kPre, dim3(NSLICE + NBLK_LR), dim3(256), 0, stream,
                       W1, W2, b1, b2, W, al, ar, bias, wlr, c0, bgvpar, wvpar);
    hipLaunchKernelGGL(kNode, dim3((N_NODES + 127) / 128), dim3(256), 0, stream,
                       feats, wlr, wvpar, (float4*)sn, (float4*)er);
    hipLaunchKernelGGL(kScan, dim3(NC * NR), dim3(256), 0, stream,
                       src, dst, (const float4*)sn, (const float4*)er, par);
    hipLaunchKernelGGL(kFinal, dim3((N_GRAPHS + 3) / 4), dim3(256), 0, stream,
                       par, bgvpar, c0, y);
}